// Round 16
// baseline (312.092 us; speedup 1.0000x reference)
//
#include <hip/hip_runtime.h>
#include <cstdint>
#include <cstddef>

#define NN 50000
#define HD 256
#define NCH 3

typedef __attribute__((ext_vector_type(8))) short shortx8;
typedef __attribute__((ext_vector_type(4))) float floatx4;
typedef __attribute__((ext_vector_type(16))) float floatx16;

__device__ __forceinline__ unsigned short f2bf(float x) {
    union { float f; uint32_t u; } v; v.f = x;
    uint32_t r = v.u + 0x7fffu + ((v.u >> 16) & 1u);   // RNE
    return (unsigned short)(r >> 16);
}
__device__ __forceinline__ float bf2f(unsigned short u) {
    union { uint32_t u; float f; } v; v.u = ((uint32_t)u) << 16; return v.f;
}
__device__ __forceinline__ uint32_t cvtpk(float a, float b) {
    uint32_t r;
    asm("v_cvt_pk_bf16_f32 %0, %1, %2" : "=v"(r) : "v"(a), "v"(b));
    return r;
}
__device__ __forceinline__ float sigf(float x) {
    return 1.0f / (1.0f + __expf(-x));
}
__device__ __forceinline__ float tanhfast(float x) {
    return 1.0f - 2.0f / (__expf(2.0f * x) + 1.0f);
}
__device__ __forceinline__ floatx16 mfma32(shortx8 a, shortx8 b, floatx16 c) {
    return __builtin_amdgcn_mfma_f32_32x32x16_bf16(a, b, c, 0, 0, 0);
}
// async global->LDS, 16B per lane; LDS dest = wave-uniform base + lane*16
__device__ __forceinline__ void glds16(const void* g, void* l) {
    __builtin_amdgcn_global_load_lds(
        (const __attribute__((address_space(1))) void*)g,
        (__attribute__((address_space(3))) void*)l, 16, 0, 0);
}

// ===========================================================================
// Weight prep (verified r8): fp32 [out,in] -> bf16 frags for 32x32x16 MFMA.
// fi = ((d*32 + tile)*16 + ks)*64 + lane; tile 0..7 F, 8..15 I, 16..23 O,
// 24..31 U. lane l: wcol = tile*32+(l&31), k = ks*16+(l>>5)*8+e.
// ===========================================================================
__global__ void prep_fused32(const float* __restrict__ U_f,
                             const float* __restrict__ U_iou,
                             unsigned short* __restrict__ wsB) {
    int idx = blockIdx.x * 256 + threadIdx.x;
    int lane = idx & 63;
    int ks   = (idx >> 6) & 15;
    int tile = (idx >> 10) & 31;
    int d    = idx >> 15;
    if (d >= NCH) return;
    int col = tile * 32 + (lane & 31);
    int k0  = ks * 16 + (lane >> 5) * 8;
    const float* src = (col < 256)
        ? (U_f   + (((size_t)d * 256 + col)         * 256 + k0))
        : (U_iou + (((size_t)d * 768 + (col - 256)) * 256 + k0));
    shortx8 o;
    #pragma unroll
    for (int e = 0; e < 8; ++e) o[e] = (short)f2bf(src[e]);
    reinterpret_cast<shortx8*>(wsB)[idx] = o;
}

// ---------------------------------------------------------------------------
// conv_nh (verified r12-r15): nh fp32 -> bf16, chunk-swizzled per 64-k slab:
// dst[r][S*64 + (c ^ (r&7))*8 + e]  (swizzle on low 3 bits of chunk index).
// ---------------------------------------------------------------------------
__global__ __launch_bounds__(256) void conv_nh(
    const float* __restrict__ nh, unsigned short* __restrict__ dst,
    int base, int count)
{
    int total = count * 96;
    for (int id = blockIdx.x * 256 + threadIdx.x; id < total;
         id += gridDim.x * 256) {
        int r = id / 96;
        int q = id - r * 96;
        const float4* s4 = reinterpret_cast<const float4*>(
            nh + (size_t)(base + r) * 768 + q * 8);
        float4 a = s4[0], b = s4[1];
        union { uint32_t u[4]; shortx8 v; } o;
        o.u[0] = cvtpk(a.x, a.y); o.u[1] = cvtpk(a.z, a.w);
        o.u[2] = cvtpk(b.x, b.y); o.u[3] = cvtpk(b.z, b.w);
        int S = q >> 3, c = q & 7;
        *reinterpret_cast<shortx8*>(
            dst + (size_t)r * 768 + S * 64 + ((c ^ (r & 7)) * 8)) = o.v;
    }
}

// ---------------------------------------------------------------------------
// fused_v2: r8's verified fused kernel (283 us) with the staging replaced by
// async glds16 from pre-converted swizzled-bf16 nhb. The conv layout makes
// a LINEAR copy of nhb[r][d*256.. +256) reproduce r8's exact LDS image
// (position p of node n holds chunk p ^ (n&7)), so compute/fold/epilogue
// are byte-identical to the verified r8 path.
// 512 thr = 8 waves, 32 nodes/block; wave cg owns hidden cols [cg*32,+32):
// tiles {F cg, I 8+cg, O 16+cg, U 24+cg}; per child 16 ks x 4 MFMA;
// fold + epilogue in registers (float4-aligned global access).
// ---------------------------------------------------------------------------
__global__ __launch_bounds__(512, 4) void fused_v2(
    const unsigned short* __restrict__ nhb,   // [count][768] swizzled bf16
    const float* __restrict__ ncc,
    const float* __restrict__ f_in,
    const float* __restrict__ iou_in,
    const unsigned short* __restrict__ wsB,
    float* __restrict__ out,
    int base, int count)
{
    __shared__ unsigned short sA[NCH * 32 * 32 * 8];   // 48 KiB
    const int tid  = threadIdx.x;
    const int lb   = blockIdx.x * 32;        // chunk-local node base
    const int lane = tid & 63;
    const int cg   = tid >> 6;               // wave 0..7
    const int nl   = lane & 31;
    const int hi   = lane >> 5;
    const int colb = cg * 32 + hi * 4;
    const shortx8* Bfr = reinterpret_cast<const shortx8*>(wsB);

    // ---- stage: 6 glds16 per wave; region ri = (d, node-pair np) covers
    //      2 nodes x 256 shorts = 1024 B; lanes 0-31 -> node 2np, 32-63 -> +1.
    #pragma unroll
    for (int j = 0; j < 6; ++j) {
        int ri = j * 8 + cg;                 // 0..47
        int d  = ri >> 4;
        int np = ri & 15;
        int r  = lb + 2 * np + (lane >> 5);
        if (r > count - 1) r = count - 1;
        glds16(nhb + (size_t)r * 768 + d * 256 + (lane & 31) * 8,
               (void*)(sA + ri * 512));
    }
    __syncthreads();

    const int  ln    = lb + nl;              // chunk-local node
    const bool valid = (ln < count);
    const int  n     = base + ln;            // global node
    const int  nc_   = valid ? n : base;

    ushort4 finb[4];
    #pragma unroll
    for (int q = 0; q < 4; ++q) {
        floatx4 v = *reinterpret_cast<const floatx4*>(
            f_in + (size_t)nc_ * HD + colb + q * 8);
        finb[q] = ushort4{f2bf(v[0]), f2bf(v[1]), f2bf(v[2]), f2bf(v[3])};
    }
    float cagg[16];
    #pragma unroll
    for (int t = 0; t < 16; ++t) cagg[t] = 0.0f;
    floatx16 accI, accO, accU;
    #pragma unroll
    for (int t = 0; t < 16; ++t) { accI[t] = 0.f; accO[t] = 0.f; accU[t] = 0.f; }
    const int nsw = nl & 7;

    #pragma unroll 1
    for (int d = 0; d < NCH; ++d) {
        floatx16 accF;
        #pragma unroll
        for (int t = 0; t < 16; ++t) accF[t] = 0.0f;
        #pragma unroll 2
        for (int ks = 0; ks < 16; ++ks) {
            shortx8 aF = Bfr[((d * 32 +      cg) * 16 + ks) * 64 + lane];
            shortx8 aI = Bfr[((d * 32 +  8 + cg) * 16 + ks) * 64 + lane];
            shortx8 aO = Bfr[((d * 32 + 16 + cg) * 16 + ks) * 64 + lane];
            shortx8 aU = Bfr[((d * 32 + 24 + cg) * 16 + ks) * 64 + lane];
            int ch = (ks * 2 + hi) ^ nsw;
            shortx8 b = *reinterpret_cast<const shortx8*>(
                &sA[((d * 32 + nl) * 32 + ch) * 8]);
            accF = mfma32(aF, b, accF);
            accI = mfma32(aI, b, accI);
            accO = mfma32(aO, b, accO);
            accU = mfma32(aU, b, accU);
        }
        #pragma unroll
        for (int q = 0; q < 4; ++q) {
            floatx4 ncr = *reinterpret_cast<const floatx4*>(
                ncc + (size_t)nc_ * (NCH * HD) + d * HD + colb + q * 8);
            cagg[q*4+0] += sigf(accF[q*4+0] + bf2f(finb[q].x)) * ncr[0];
            cagg[q*4+1] += sigf(accF[q*4+1] + bf2f(finb[q].y)) * ncr[1];
            cagg[q*4+2] += sigf(accF[q*4+2] + bf2f(finb[q].z)) * ncr[2];
            cagg[q*4+3] += sigf(accF[q*4+3] + bf2f(finb[q].w)) * ncr[3];
        }
    }
    if (valid) {
        #pragma unroll
        for (int q = 0; q < 4; ++q) {
            int col = colb + q * 8;
            size_t b2 = (size_t)n * 768 + col;
            floatx4 i4 = *reinterpret_cast<const floatx4*>(iou_in + b2);
            floatx4 o4 = *reinterpret_cast<const floatx4*>(iou_in + b2 + 256);
            floatx4 u4 = *reinterpret_cast<const floatx4*>(iou_in + b2 + 512);
            floatx4 cc, hh;
            #pragma unroll
            for (int r = 0; r < 4; ++r) {
                int t = q * 4 + r;
                float c = sigf(accI[t] + 2.f*i4[r]) * tanhfast(accU[t] + 2.f*u4[r])
                          + cagg[t];
                cc[r] = c;
                hh[r] = sigf(accO[t] + 2.f*o4[r]) * tanhfast(c);
            }
            *reinterpret_cast<floatx4*>(out + (size_t)n * HD + col) = hh;
            *reinterpret_cast<floatx4*>(out + (size_t)(NN + n) * HD + col) = cc;
        }
    }
}

// ===========================================================================
// ULTRA-FALLBACK (r8 original, verified 283 us): reads fp32 nh directly.
// Used only when ws cannot hold even a minimal bf16 nh chunk.
// ===========================================================================
__global__ __launch_bounds__(512, 4) void fused_main(
    const float* __restrict__ nh, const float* __restrict__ ncc,
    const float* __restrict__ f_in, const float* __restrict__ iou_in,
    const unsigned short* __restrict__ wsB, float* __restrict__ out)
{
    __shared__ unsigned short sA[NCH * 32 * 32 * 8];
    const int tid  = threadIdx.x;
    const int nb   = blockIdx.x * 32;
    const int lane = tid & 63;
    const int cg   = tid >> 6;
    const int nl   = lane & 31;
    const int hi   = lane >> 5;
    const int colb = cg * 32 + hi * 4;
    const shortx8* Bfr = reinterpret_cast<const shortx8*>(wsB);
    #pragma unroll
    for (int i = 0; i < 6; ++i) {
        int c = i * 512 + tid;
        int d = c >> 10, node = (c >> 5) & 31, slot = c & 31;
        int gn = nb + node;
        shortx8 o;
        if (gn < NN) {
            const float4* q = reinterpret_cast<const float4*>(
                nh + ((size_t)gn * (NCH * HD) + d * HD + slot * 8));
            float4 a = q[0], b = q[1];
            union { uint32_t u[4]; shortx8 v; } t;
            t.u[0] = cvtpk(a.x, a.y); t.u[1] = cvtpk(a.z, a.w);
            t.u[2] = cvtpk(b.x, b.y); t.u[3] = cvtpk(b.z, b.w);
            o = t.v;
        } else {
            for (int e = 0; e < 8; ++e) o[e] = 0;
        }
        int idx = (d * 32 + node) * 32 + (slot ^ (node & 7));
        *reinterpret_cast<shortx8*>(&sA[idx * 8]) = o;
    }
    __syncthreads();
    const int  n     = nb + nl;
    const bool valid = (n < NN);
    const int  nc_   = valid ? n : (NN - 1);
    ushort4 finb[4];
    #pragma unroll
    for (int q = 0; q < 4; ++q) {
        floatx4 v = *reinterpret_cast<const floatx4*>(
            f_in + (size_t)nc_ * HD + colb + q * 8);
        finb[q] = ushort4{f2bf(v[0]), f2bf(v[1]), f2bf(v[2]), f2bf(v[3])};
    }
    float cagg[16];
    #pragma unroll
    for (int t = 0; t < 16; ++t) cagg[t] = 0.0f;
    floatx16 accI, accO, accU;
    #pragma unroll
    for (int t = 0; t < 16; ++t) { accI[t] = 0.f; accO[t] = 0.f; accU[t] = 0.f; }
    const int nsw = nl & 7;
    #pragma unroll 1
    for (int d = 0; d < NCH; ++d) {
        floatx16 accF;
        #pragma unroll
        for (int t = 0; t < 16; ++t) accF[t] = 0.0f;
        #pragma unroll 2
        for (int ks = 0; ks < 16; ++ks) {
            shortx8 aF = Bfr[((d * 32 +      cg) * 16 + ks) * 64 + lane];
            shortx8 aI = Bfr[((d * 32 +  8 + cg) * 16 + ks) * 64 + lane];
            shortx8 aO = Bfr[((d * 32 + 16 + cg) * 16 + ks) * 64 + lane];
            shortx8 aU = Bfr[((d * 32 + 24 + cg) * 16 + ks) * 64 + lane];
            int ch = (ks * 2 + hi) ^ nsw;
            shortx8 b = *reinterpret_cast<const shortx8*>(
                &sA[((d * 32 + nl) * 32 + ch) * 8]);
            accF = mfma32(aF, b, accF);
            accI = mfma32(aI, b, accI);
            accO = mfma32(aO, b, accO);
            accU = mfma32(aU, b, accU);
        }
        #pragma unroll
        for (int q = 0; q < 4; ++q) {
            floatx4 ncr = *reinterpret_cast<const floatx4*>(
                ncc + (size_t)nc_ * (NCH * HD) + d * HD + colb + q * 8);
            cagg[q*4+0] += sigf(accF[q*4+0] + bf2f(finb[q].x)) * ncr[0];
            cagg[q*4+1] += sigf(accF[q*4+1] + bf2f(finb[q].y)) * ncr[1];
            cagg[q*4+2] += sigf(accF[q*4+2] + bf2f(finb[q].z)) * ncr[2];
            cagg[q*4+3] += sigf(accF[q*4+3] + bf2f(finb[q].w)) * ncr[3];
        }
    }
    if (valid) {
        #pragma unroll
        for (int q = 0; q < 4; ++q) {
            int col = colb + q * 8;
            size_t b2 = (size_t)n * 768 + col;
            floatx4 i4 = *reinterpret_cast<const floatx4*>(iou_in + b2);
            floatx4 o4 = *reinterpret_cast<const floatx4*>(iou_in + b2 + 256);
            floatx4 u4 = *reinterpret_cast<const floatx4*>(iou_in + b2 + 512);
            floatx4 cc, hh;
            #pragma unroll
            for (int r = 0; r < 4; ++r) {
                int t = q * 4 + r;
                float c = sigf(accI[t] + 2.f*i4[r]) * tanhfast(accU[t] + 2.f*u4[r])
                          + cagg[t];
                cc[r] = c;
                hh[r] = sigf(accO[t] + 2.f*o4[r]) * tanhfast(c);
            }
            *reinterpret_cast<floatx4*>(out + (size_t)n * HD + col) = hh;
            *reinterpret_cast<floatx4*>(out + (size_t)(NN + n) * HD + col) = cc;
        }
    }
}

// ===========================================================================
extern "C" void kernel_launch(void* const* d_in, const int* in_sizes, int n_in,
                              void* d_out, int out_size, void* d_ws, size_t ws_size,
                              hipStream_t stream) {
    const float* nh     = (const float*)d_in[0];
    const float* ncc    = (const float*)d_in[1];
    const float* f_in   = (const float*)d_in[2];
    const float* iou_in = (const float*)d_in[3];
    const float* U_f    = (const float*)d_in[4];
    const float* U_iou  = (const float*)d_in[5];
    unsigned short* wsB = (unsigned short*)d_ws;

    const size_t FRAG_BYTES = (size_t)98304 * 16;    // 1.5 MiB
    const size_t DATA_OFF   = (size_t)2 << 20;       // nhb chunk at +2 MiB

    long long cmax = 0;
    if (ws_size > DATA_OFF)
        cmax = (long long)((ws_size - DATA_OFF) / 1536);   // bf16 nh bytes/node
    cmax = (cmax / 128) * 128;

    if (cmax >= 128) {
        hipLaunchKernelGGL(prep_fused32, dim3(384), dim3(256), 0, stream,
                           U_f, U_iou, wsB);
        unsigned short* nhb = (unsigned short*)((char*)d_ws + DATA_OFF);
        int base = 0;
        while (base < NN) {
            long long rem = NN - base;
            int count = (int)(rem < cmax ? rem : cmax);

            int cgrid = (count * 96 + 255) / 256;
            if (cgrid > 2048) cgrid = 2048;
            hipLaunchKernelGGL(conv_nh, dim3(cgrid), dim3(256), 0, stream,
                               nh, nhb, base, count);

            hipLaunchKernelGGL(fused_v2, dim3((count + 31) / 32), dim3(512), 0,
                               stream, nhb, ncc, f_in, iou_in, wsB,
                               (float*)d_out, base, count);
            base += count;
        }
    } else if (ws_size >= FRAG_BYTES) {
        hipLaunchKernelGGL(prep_fused32, dim3(384), dim3(256), 0, stream,
                           U_f, U_iou, wsB);
        hipLaunchKernelGGL(fused_main, dim3((NN + 31) / 32), dim3(512), 0,
                           stream, nh, ncc, f_in, iou_in, wsB, (float*)d_out);
    }
}